// Round 1
// baseline (91.475 us; speedup 1.0000x reference)
//
#include <hip/hip_runtime.h>

// out[i] = sum_b sum_t X[b, (i - t) mod D] * Y[b, t]
// B = 128, D = 1024, fp32.
//
// Grid: 256 blocks = (b, t-half). Block: 256 threads.
// Each block stages X[b,:] replicated 2x into LDS (2048 floats) so the
// circular index (i - t) mod D becomes xsh[i - t + 1024] (plain offset).
// Thread tid owns 4 consecutive outputs i = 4*tid + {0..3}; t unrolled by 8.
// X window per group: 12 floats via 3 aligned ds_read_b128, lane stride 16B
// (perfect coalesced b128, conflict-free). Y is wave-uniform -> global/SMEM.
// Partial sums combined across blocks with fp32 atomicAdd into zeroed d_out.

#define CC_D 1024

__global__ __launch_bounds__(256) void ccsum_kernel(
    const float* __restrict__ X, const float* __restrict__ Y,
    float* __restrict__ out) {
  const int bc   = blockIdx.x;   // 0..255
  const int b    = bc >> 1;
  const int t0h  = (bc & 1) * 512;
  const int tid  = threadIdx.x;

  __shared__ __align__(16) float xsh[2 * CC_D];

  // Stage X row, replicated twice (1024 floats -> 2048).
  const float4* X4 = (const float4*)(X + b * CC_D);
  float4 xv = X4[tid];
  ((float4*)xsh)[tid]       = xv;
  ((float4*)xsh)[tid + 256] = xv;
  __syncthreads();

  const float* ybase = Y + b * CC_D + t0h;        // wave-uniform accesses
  const float* xs    = xsh + 1024 - t0h + 4 * tid; // per-thread shifted base

  float a0 = 0.f, a1 = 0.f, a2 = 0.f, a3 = 0.f;

#pragma unroll 4
  for (int tg = 0; tg < 64; ++tg) {
    // y[t0h + 8*tg + r], r = 0..7  (uniform -> s_load/VMEM, not LDS)
    const float4 ya = ((const float4*)(ybase + 8 * tg))[0];
    const float4 yb = ((const float4*)(ybase + 8 * tg))[1];

    // X window W[j] = xs[-8*tg - 8 + j], j = 0..11 (16B-aligned, 3x b128)
    const float4 w0 = *(const float4*)(xs - 8 * tg - 8);
    const float4 w1 = *(const float4*)(xs - 8 * tg - 4);
    const float4 w2 = *(const float4*)(xs - 8 * tg);

    const float W[12] = {w0.x, w0.y, w0.z, w0.w,
                         w1.x, w1.y, w1.z, w1.w,
                         w2.x, w2.y, w2.z, w2.w};
    const float yv[8] = {ya.x, ya.y, ya.z, ya.w, yb.x, yb.y, yb.z, yb.w};

#pragma unroll
    for (int r = 0; r < 8; ++r) {
      // acc[q] += X[(i - t) mod D] * y[t];  i = 4*tid + q, t = t0h + 8*tg + r
      // index: W[q + 8 - r]
      a0 += W[8 - r]  * yv[r];
      a1 += W[9 - r]  * yv[r];
      a2 += W[10 - r] * yv[r];
      a3 += W[11 - r] * yv[r];
    }
  }

  const int i0 = 4 * tid;
  atomicAdd(&out[i0 + 0], a0);
  atomicAdd(&out[i0 + 1], a1);
  atomicAdd(&out[i0 + 2], a2);
  atomicAdd(&out[i0 + 3], a3);
}

extern "C" void kernel_launch(void* const* d_in, const int* in_sizes, int n_in,
                              void* d_out, int out_size, void* d_ws,
                              size_t ws_size, hipStream_t stream) {
  const float* X = (const float*)d_in[0];  // (128, 1024) f32
  const float* Y = (const float*)d_in[1];  // (128, 1024) f32
  float* out = (float*)d_out;              // 1024 f32

  // d_out is poisoned 0xAA before every launch -> zero it (graph-capturable).
  hipMemsetAsync(out, 0, (size_t)out_size * sizeof(float), stream);
  ccsum_kernel<<<256, 256, 0, stream>>>(X, Y, out);
}

// Round 2
// 73.106 us; speedup vs baseline: 1.2513x; 1.2513x over previous
//
#include <hip/hip_runtime.h>

// out[i] = sum_b sum_t X[b, (i - t) mod D] * Y[b, t],  B=128, D=1024, fp32.
//
// Kernel 1 (cc_partial): grid 1024 = (b=128) x (tslice=8), 256 threads.
//   - X[b,:] staged 2x-replicated in LDS (2048 f) -> circular index is a
//     plain offset.
//   - thread = (ig = tid&127 -> outputs 8*ig..+7, ts = tid>>7 -> 64-t sub).
//   - sliding 16-float register window, shift by 8 per t-group: only two
//     ds_read_b128 per 64 FMAs -> VALU-bound, not LDS-bound.
//   - Y accesses are wave-uniform (readfirstlane'd ts) -> scalar path.
//   - in-block reduce over ts through LDS; block writes 1024 partials to ws.
// Kernel 2 (cc_reduce): 256 blocks x 256 thr; block j sums ws[:,4j..4j+3]
//   over 1024 block-partials, LDS tree, writes out directly (no memset,
//   no atomics anywhere).

#define CC_D 1024

__global__ __launch_bounds__(256) void cc_partial_kernel(
    const float* __restrict__ X, const float* __restrict__ Y,
    float* __restrict__ ws) {
  const int blk    = blockIdx.x;   // 0..1023
  const int b      = blk >> 3;     // 0..127
  const int tslice = blk & 7;      // 0..7 (128 t's each)
  const int tid    = threadIdx.x;
  const int ig     = tid & 127;    // outputs i = 8*ig .. 8*ig+7
  const int ts     = tid >> 7;     // 0/1: 64-t subrange (wave-uniform)

  __shared__ __align__(16) float xsh[2 * CC_D];

  // Stage X row, replicated twice.
  const float4 xv = ((const float4*)(X + b * CC_D))[tid];
  ((float4*)xsh)[tid]       = xv;
  ((float4*)xsh)[tid + 256] = xv;
  __syncthreads();

  const int ts_u   = __builtin_amdgcn_readfirstlane(ts);
  const int tstart = tslice * 128 + ts_u * 64;   // uniform per wave
  const float* yb  = Y + b * CC_D + tstart;      // uniform per wave

  // Window for t-group g: W[j] = xsh[base0 - 8g + j], j=0..15.
  // acc[q] += W[8 + q - r] * y[tstart + 8g + r]   (q,r in 0..7)
  const float* base0 = xsh + CC_D + 8 * ig - tstart - 8;

  float acc[8];
#pragma unroll
  for (int q = 0; q < 8; ++q) acc[q] = 0.f;

  float W[16];
#pragma unroll
  for (int j = 0; j < 4; ++j) {
    const float4 w = ((const float4*)base0)[j];
    W[4 * j + 0] = w.x; W[4 * j + 1] = w.y;
    W[4 * j + 2] = w.z; W[4 * j + 3] = w.w;
  }

#pragma unroll
  for (int g = 0; g < 8; ++g) {
    float y[8];
#pragma unroll
    for (int j = 0; j < 2; ++j) {
      const float4 yv = ((const float4*)(yb + 8 * g))[j];
      y[4 * j + 0] = yv.x; y[4 * j + 1] = yv.y;
      y[4 * j + 2] = yv.z; y[4 * j + 3] = yv.w;
    }

#pragma unroll
    for (int r = 0; r < 8; ++r)
#pragma unroll
      for (int q = 0; q < 8; ++q)
        acc[q] += W[8 + q - r] * y[r];

    if (g < 7) {
      // Slide window down by 8: upper half <- lower half, load new lower 8.
#pragma unroll
      for (int j = 0; j < 8; ++j) W[8 + j] = W[j];
      const float* nb = base0 - 8 * (g + 1);
      const float4 w0 = ((const float4*)nb)[0];
      const float4 w1 = ((const float4*)nb)[1];
      W[0] = w0.x; W[1] = w0.y; W[2] = w0.z; W[3] = w0.w;
      W[4] = w1.x; W[5] = w1.y; W[6] = w1.z; W[7] = w1.w;
    }
  }

  // In-block reduce over ts (reuse xsh), then write 1024 partials to ws.
  __syncthreads();
  float4* st = (float4*)(xsh + ts * CC_D + 8 * ig);
  st[0] = make_float4(acc[0], acc[1], acc[2], acc[3]);
  st[1] = make_float4(acc[4], acc[5], acc[6], acc[7]);
  __syncthreads();

  const float4 s0 = ((const float4*)xsh)[tid];
  const float4 s1 = ((const float4*)(xsh + CC_D))[tid];
  float4 r;
  r.x = s0.x + s1.x; r.y = s0.y + s1.y;
  r.z = s0.z + s1.z; r.w = s0.w + s1.w;
  ((float4*)(ws + (size_t)blk * CC_D))[tid] = r;
}

__global__ __launch_bounds__(256) void cc_reduce_kernel(
    const float* __restrict__ ws, float* __restrict__ out) {
  const int j   = blockIdx.x;    // outputs 4j..4j+3
  const int tid = threadIdx.x;

  __shared__ float4 red[256];

  float4 s = make_float4(0.f, 0.f, 0.f, 0.f);
#pragma unroll
  for (int p = 0; p < 4; ++p) {
    const float4 v =
        *(const float4*)(ws + (size_t)(tid + 256 * p) * CC_D + 4 * j);
    s.x += v.x; s.y += v.y; s.z += v.z; s.w += v.w;
  }
  red[tid] = s;
  __syncthreads();

  for (int st = 128; st > 0; st >>= 1) {
    if (tid < st) {
      const float4 o = red[tid + st];
      red[tid].x += o.x; red[tid].y += o.y;
      red[tid].z += o.z; red[tid].w += o.w;
    }
    __syncthreads();
  }

  if (tid == 0) ((float4*)out)[j] = red[0];
}

extern "C" void kernel_launch(void* const* d_in, const int* in_sizes, int n_in,
                              void* d_out, int out_size, void* d_ws,
                              size_t ws_size, hipStream_t stream) {
  const float* X = (const float*)d_in[0];  // (128, 1024) f32
  const float* Y = (const float*)d_in[1];  // (128, 1024) f32
  float* out = (float*)d_out;              // 1024 f32
  float* ws  = (float*)d_ws;               // >= 4 MB used

  cc_partial_kernel<<<1024, 256, 0, stream>>>(X, Y, ws);
  cc_reduce_kernel<<<256, 256, 0, stream>>>(ws, out);
}

// Round 3
// 70.346 us; speedup vs baseline: 1.3004x; 1.0392x over previous
//
#include <hip/hip_runtime.h>

// out[i] = sum_b sum_t X[b, (i - t) mod D] * Y[b, t],  B=128, D=1024, fp32.
//
// Kernel 1 (cc_partial): grid 1024 = (b=128) x (tslice=8 of 128 t), 512 thr
//   = 8 waves; 4 blocks/CU -> 32 waves/CU (hardware max occupancy).
//   - X[b,:] staged 2x-replicated into LDS with a rotate-swizzle
//     (phys float4 = (f&~7)|((f+(f>>3))&7)) so window reads at lane stride
//     2 float4s hit all 8 bank-quads -> conflict-free b128.
//   - Y slice (128 floats) staged to LDS; inner-loop y reads are
//     wave-uniform LDS broadcasts. NO global loads in the main loop.
//   - thread (ig = tid&127, ts = tid>>7): outputs i = 8*ig..+7, t-range
//     32 (ts quarter). Sliding 16-float register window, 2 new b128 per
//     8 t. 256 FMAs/thread straight-line.
//   - in-LDS reduce over 4 ts -> 1024 partials/block -> ws row.
// Kernel 2 (cc_reduce): 256 blocks x 256 thr; block j sums ws[:, 4j..4j+3]
//   over 1024 rows, LDS tree, writes out. No atomics, no memset.

#define CC_D 1024

__device__ __forceinline__ int swz(int f) {
  // rotate each row of 8 float4-quads by the row index
  return (f & ~7) | ((f + (f >> 3)) & 7);
}

__global__ __launch_bounds__(512, 8) void cc_partial_kernel(
    const float* __restrict__ X, const float* __restrict__ Y,
    float* __restrict__ ws) {
  const int blk    = blockIdx.x;   // 0..1023
  const int b      = blk >> 3;     // 0..127
  const int tslice = blk & 7;      // 128 t's each
  const int tid    = threadIdx.x;  // 0..511
  const int ig     = tid & 127;    // outputs i = 8*ig .. 8*ig+7
  const int ts     = tid >> 7;     // 0..3: 32-t quarter (wave-uniform)

  __shared__ __align__(16) float smem[4096 + 128];
  float4* sm4 = (float4*)smem;     // X area: logical float4 0..511 (swizzled)
  float*  ysh = smem + 4096;       // 128 floats

  // Stage X row (swizzled, replicated 2x) and Y slice.
  if (tid < 256) {
    const float4 v = ((const float4*)(X + b * CC_D))[tid];
    sm4[swz(tid)]       = v;
    sm4[swz(tid + 256)] = v;
  }
  if (tid < 32) {
    ((float4*)ysh)[tid] =
        ((const float4*)(Y + b * CC_D + tslice * 128))[tid];
  }
  __syncthreads();

  const int ts_u = __builtin_amdgcn_readfirstlane(ts);
  const int t0   = tslice * 128 + ts_u * 32;

  // Window group g (t = t0 + 8g + r): W[j] = xlog[base_g + j], j=0..15,
  // base_g = 1024 + 8*ig - t0 - 8 - 8g.  acc[q] += W[8+q-r] * y[r].
  const int f0 = 254 + 2 * ig - (t0 >> 2);  // float4 idx of base_0

  float W[16];
#pragma unroll
  for (int m = 0; m < 4; ++m) {
    const float4 w = sm4[swz(f0 + m)];
    W[4 * m + 0] = w.x; W[4 * m + 1] = w.y;
    W[4 * m + 2] = w.z; W[4 * m + 3] = w.w;
  }

  float acc[8];
#pragma unroll
  for (int q = 0; q < 8; ++q) acc[q] = 0.f;

#pragma unroll
  for (int g = 0; g < 4; ++g) {
    const float4 ya = ((const float4*)ysh)[ts_u * 8 + 2 * g];
    const float4 yb = ((const float4*)ysh)[ts_u * 8 + 2 * g + 1];
    const float y[8] = {ya.x, ya.y, ya.z, ya.w, yb.x, yb.y, yb.z, yb.w};

#pragma unroll
    for (int r = 0; r < 8; ++r)
#pragma unroll
      for (int q = 0; q < 8; ++q)
        acc[q] += W[8 + q - r] * y[r];

    if (g < 3) {
      // slide window down 8 floats; load 2 new float4
#pragma unroll
      for (int j = 0; j < 8; ++j) W[8 + j] = W[j];
      const float4 w0 = sm4[swz(f0 - 2 * (g + 1))];
      const float4 w1 = sm4[swz(f0 - 2 * (g + 1) + 1)];
      W[0] = w0.x; W[1] = w0.y; W[2] = w0.z; W[3] = w0.w;
      W[4] = w1.x; W[5] = w1.y; W[6] = w1.z; W[7] = w1.w;
    }
  }

  // In-LDS reduce over ts (overwrite X area after all reads done).
  __syncthreads();
  float4* st = (float4*)(smem + ts * CC_D + 8 * ig);
  st[0] = make_float4(acc[0], acc[1], acc[2], acc[3]);
  st[1] = make_float4(acc[4], acc[5], acc[6], acc[7]);
  __syncthreads();

  if (tid < 256) {
    float4 s = make_float4(0.f, 0.f, 0.f, 0.f);
#pragma unroll
    for (int sidx = 0; sidx < 4; ++sidx) {
      const float4 v = sm4[sidx * 256 + tid];
      s.x += v.x; s.y += v.y; s.z += v.z; s.w += v.w;
    }
    ((float4*)ws)[blk * 256 + tid] = s;
  }
}

__global__ __launch_bounds__(256) void cc_reduce_kernel(
    const float* __restrict__ ws, float* __restrict__ out) {
  const int j   = blockIdx.x;    // outputs 4j..4j+3
  const int tid = threadIdx.x;

  __shared__ float4 red[256];

  float4 s = make_float4(0.f, 0.f, 0.f, 0.f);
#pragma unroll
  for (int p = 0; p < 4; ++p) {
    const float4 v = ((const float4*)ws)[(size_t)(tid + 256 * p) * 256 + j];
    s.x += v.x; s.y += v.y; s.z += v.z; s.w += v.w;
  }
  red[tid] = s;
  __syncthreads();

  for (int st = 128; st > 0; st >>= 1) {
    if (tid < st) {
      const float4 o = red[tid + st];
      red[tid].x += o.x; red[tid].y += o.y;
      red[tid].z += o.z; red[tid].w += o.w;
    }
    __syncthreads();
  }

  if (tid == 0) ((float4*)out)[j] = red[0];
}

extern "C" void kernel_launch(void* const* d_in, const int* in_sizes, int n_in,
                              void* d_out, int out_size, void* d_ws,
                              size_t ws_size, hipStream_t stream) {
  const float* X = (const float*)d_in[0];  // (128, 1024) f32
  const float* Y = (const float*)d_in[1];  // (128, 1024) f32
  float* out = (float*)d_out;              // 1024 f32
  float* ws  = (float*)d_ws;               // 4 MB used

  cc_partial_kernel<<<1024, 512, 0, stream>>>(X, Y, ws);
  cc_reduce_kernel<<<256, 256, 0, stream>>>(ws, out);
}

// Round 4
// 64.302 us; speedup vs baseline: 1.4226x; 1.0940x over previous
//
#include <hip/hip_runtime.h>

// out[i] = sum_b sum_t X[b, (i - t) mod D] * Y[b, t],  B=128, D=1024, fp32.
//
// Kernel 1 (cc_partial): grid 1024 = (b=128) x (tslice=8 of 128 t), 512 thr.
//   - X[b,:] staged 2x-replicated in LDS with rotate-swizzle -> window
//     reads are conflict-free b128.
//   - Y read DIRECTLY from global with wave-uniform addresses (scalar/VMEM
//     path) -> LDS pipe only carries the X window (10 b128/thread).
//   - 8 outputs x 32 t per thread, sliding 16-float register window.
//   - ts-reduce through LDS, then TRANSPOSED partial store: thread i4
//     stores float4 (outputs 4*i4..+3) to ws4[i4*1024 + blk] (one scattered
//     b128/lane, fire-and-forget).
// Kernel 2 (cc_reduce): 256 blocks x 256 thr; block j reads ws4 row j
//   (16 KB CONTIGUOUS, coalesced), per-lane float4 sums, wave butterfly,
//   4 wave-partials via LDS, thread 0 writes out4[j]. No atomics, no memset.

#define CC_D 1024

__device__ __forceinline__ int swz(int f) {
  // rotate each 8-float4 row by the row index -> balanced banks at lane
  // stride 2 float4
  return (f & ~7) | ((f + (f >> 3)) & 7);
}

__global__ __launch_bounds__(512, 8) void cc_partial_kernel(
    const float* __restrict__ X, const float* __restrict__ Y,
    float* __restrict__ ws) {
  const int blk    = blockIdx.x;   // 0..1023
  const int b      = blk >> 3;     // 0..127
  const int tslice = blk & 7;      // 128 t's each
  const int tid    = threadIdx.x;  // 0..511
  const int ig     = tid & 127;    // outputs i = 8*ig .. 8*ig+7
  const int ts     = tid >> 7;     // 0..3: 32-t quarter (uniform per wave)

  __shared__ __align__(16) float smem[4096];
  float4* sm4 = (float4*)smem;     // X area: logical float4 0..511, swizzled

  // Stage X row (swizzled, replicated 2x).
  if (tid < 256) {
    const float4 v = ((const float4*)(X + b * CC_D))[tid];
    sm4[swz(tid)]       = v;
    sm4[swz(tid + 256)] = v;
  }
  __syncthreads();

  const int ts_u = __builtin_amdgcn_readfirstlane(ts);
  const int t0   = tslice * 128 + ts_u * 32;
  const float* yb = Y + b * CC_D + t0;       // wave-uniform base

  // Window group g (t = t0 + 8g + r): W[j] = xlog[base_g + j], j=0..15,
  // base_g = 1024 + 8*ig - t0 - 8 - 8g.  acc[q] += W[8+q-r] * y[r].
  const int f0 = 254 + 2 * ig - (t0 >> 2);   // float4 idx of base_0

  float W[16];
#pragma unroll
  for (int m = 0; m < 4; ++m) {
    const float4 w = sm4[swz(f0 + m)];
    W[4 * m + 0] = w.x; W[4 * m + 1] = w.y;
    W[4 * m + 2] = w.z; W[4 * m + 3] = w.w;
  }

  float acc[8];
#pragma unroll
  for (int q = 0; q < 8; ++q) acc[q] = 0.f;

#pragma unroll
  for (int g = 0; g < 4; ++g) {
    // y: wave-uniform global reads (scalar-load eligible)
    const float4 ya = ((const float4*)(yb + 8 * g))[0];
    const float4 yc = ((const float4*)(yb + 8 * g))[1];
    const float y[8] = {ya.x, ya.y, ya.z, ya.w, yc.x, yc.y, yc.z, yc.w};

#pragma unroll
    for (int r = 0; r < 8; ++r)
#pragma unroll
      for (int q = 0; q < 8; ++q)
        acc[q] += W[8 + q - r] * y[r];

    if (g < 3) {
#pragma unroll
      for (int j = 0; j < 8; ++j) W[8 + j] = W[j];
      const float4 w0 = sm4[swz(f0 - 2 * (g + 1))];
      const float4 w1 = sm4[swz(f0 - 2 * (g + 1) + 1)];
      W[0] = w0.x; W[1] = w0.y; W[2] = w0.z; W[3] = w0.w;
      W[4] = w1.x; W[5] = w1.y; W[6] = w1.z; W[7] = w1.w;
    }
  }

  // In-LDS reduce over the 4 ts quarters (X area no longer needed).
  __syncthreads();
  float4* st = (float4*)(smem + ts * CC_D + 8 * ig);
  st[0] = make_float4(acc[0], acc[1], acc[2], acc[3]);
  st[1] = make_float4(acc[4], acc[5], acc[6], acc[7]);
  __syncthreads();

  if (tid < 256) {
    float4 s = make_float4(0.f, 0.f, 0.f, 0.f);
#pragma unroll
    for (int sidx = 0; sidx < 4; ++sidx) {
      const float4 v = ((const float4*)smem)[sidx * 256 + tid];
      s.x += v.x; s.y += v.y; s.z += v.z; s.w += v.w;
    }
    // transposed partial store: ws4[i4][blk], i4 = tid -> outputs 4*i4..+3
    ((float4*)ws)[(size_t)tid * 1024 + blk] = s;
  }
}

__global__ __launch_bounds__(256) void cc_reduce_kernel(
    const float* __restrict__ ws, float* __restrict__ out) {
  const int j   = blockIdx.x;        // outputs 4j..4j+3
  const int tid = threadIdx.x;
  const int l   = tid & 63;
  const int w   = tid >> 6;          // wave 0..3

  __shared__ float4 red[4];

  const float4* row = (const float4*)ws + (size_t)j * 1024;
  float4 s = make_float4(0.f, 0.f, 0.f, 0.f);
#pragma unroll
  for (int c = 0; c < 4; ++c) {
    const float4 v = row[(size_t)(c * 256 + tid)];
    s.x += v.x; s.y += v.y; s.z += v.z; s.w += v.w;
  }
  // wave butterfly on each component
#pragma unroll
  for (int o = 32; o > 0; o >>= 1) {
    s.x += __shfl_xor(s.x, o, 64);
    s.y += __shfl_xor(s.y, o, 64);
    s.z += __shfl_xor(s.z, o, 64);
    s.w += __shfl_xor(s.w, o, 64);
  }
  if (l == 0) red[w] = s;
  __syncthreads();

  if (tid == 0) {
    float4 r = red[0];
    r.x += red[1].x + red[2].x + red[3].x;
    r.y += red[1].y + red[2].y + red[3].y;
    r.z += red[1].z + red[2].z + red[3].z;
    r.w += red[1].w + red[2].w + red[3].w;
    ((float4*)out)[j] = r;
  }
}

extern "C" void kernel_launch(void* const* d_in, const int* in_sizes, int n_in,
                              void* d_out, int out_size, void* d_ws,
                              size_t ws_size, hipStream_t stream) {
  const float* X = (const float*)d_in[0];  // (128, 1024) f32
  const float* Y = (const float*)d_in[1];  // (128, 1024) f32
  float* out = (float*)d_out;              // 1024 f32
  float* ws  = (float*)d_ws;               // 4 MB used

  cc_partial_kernel<<<1024, 512, 0, stream>>>(X, Y, ws);
  cc_reduce_kernel<<<256, 256, 0, stream>>>(ws, out);
}